// Round 1
// baseline (3385.847 us; speedup 1.0000x reference)
//
#include <hip/hip_runtime.h>
#include <hip/hip_bf16.h>
#include <math.h>

// Problem constants
constexpr int N_NODES = 32768;
constexpr int LEN     = 3000;
constexpr int RED     = 146;        // conv output positions
constexpr int NCH     = 32;         // conv channels
constexpr int FIN     = 4672;       // 32*146
constexpr int HID     = 128;
constexpr int OUT3    = 64;
constexpr int E_TOT   = 32768*16;   // 524288 edges
constexpr int PG      = 64;         // nodes per graph
constexpr int EPG     = 1024;       // edges per graph
constexpr int NG      = 512;        // graphs

// ---------------------------------------------------------------- degree
__global__ void deg_init(float* deg) {
    int i = blockIdx.x*256 + threadIdx.x;
    if (i < N_NODES) deg[i] = 1.0f;     // self-loop weight
}
__global__ void deg_acc(const int* __restrict__ ei, const float* __restrict__ ew,
                        float* deg) {
    int e = blockIdx.x*256 + threadIdx.x;
    if (e < E_TOT) atomicAdd(&deg[ei[E_TOT + e]], ew[e]);
}
__global__ void dinv_k(const float* __restrict__ deg, float* dinv) {
    int i = blockIdx.x*256 + threadIdx.x;
    if (i < N_NODES) dinv[i] = rsqrtf(deg[i]);
}

// --------------------------------------------- fused conv1d + relu + GEMM1
// 32 nodes per WG, r-chunks of 6. LDS: wS 12.8K + xs 25.6K + cbuf 25.6K = 64.1KB
constexpr int RCH = 6;
constexpr int WIN = 20*RCH + 80;    // 200 floats of x per node per chunk
constexpr int CBS = 200;            // cbuf stride per m (192 used, padded)

__global__ __launch_bounds__(256) void conv_gemm1(
    const float* __restrict__ x, const float* __restrict__ cw,
    const float* __restrict__ cbn, const float* __restrict__ W1,
    float* __restrict__ z)
{
    __shared__ float wS[25*128];     // [k>>2][c][k&3]
    __shared__ float cbias[NCH];
    __shared__ float xs[32*WIN];     // [m][200]
    __shared__ float cbuf[32*CBS];   // [m][rr*32 + c]

    const int t  = threadIdx.x;
    const int n0 = blockIdx.x * 32;

    for (int i = t; i < 3200; i += 256) {
        int k = i >> 5, c = i & 31;
        wS[(k>>2)*128 + c*4 + (k&3)] = cw[c*100 + k];
    }
    if (t < NCH) cbias[t] = cbn[t];

    const int f0 = (t & 63)*2;   // GEMM: feature pair
    const int mg = t >> 6;       // GEMM: m base (0..3)
    const int c0 = (t & 15)*2;   // conv: channel pair
    const int mc = t >> 4;       // conv: m (0..15), +16 on second pass

    float a0[8], a1[8];
    #pragma unroll
    for (int k = 0; k < 8; k++) { a0[k] = 0.f; a1[k] = 0.f; }

    for (int r0 = 0; r0 < RED; r0 += RCH) {
        const int rcount = min(RCH, RED - r0);
        __syncthreads();                       // protect xs/cbuf from prev chunk readers
        {   // stage x windows: x[n, 20*r0 .. 20*r0+199]
            const int base = 20*r0;
            for (int i = t; i < 32*WIN; i += 256) {
                int m = i / WIN, off = i - m*WIN;
                int idx = base + off; idx = idx < LEN-1 ? idx : LEN-1;
                xs[i] = x[(size_t)(n0+m)*LEN + idx];
            }
        }
        __syncthreads();
        // conv: thread computes channels (c0,c0+1), node m, rr<6
        #pragma unroll
        for (int j = 0; j < 2; j++) {
            const int m = mc + 16*j;
            float o0[RCH], o1[RCH];
            #pragma unroll
            for (int rr = 0; rr < RCH; rr++) { o0[rr] = cbias[c0]; o1[rr] = cbias[c0+1]; }
            for (int k0 = 0; k0 < 100; k0 += 4) {
                const float4 wv0 = *(const float4*)&wS[(k0>>2)*128 + c0*4];
                const float4 wv1 = *(const float4*)&wS[(k0>>2)*128 + (c0+1)*4];
                #pragma unroll
                for (int rr = 0; rr < RCH; rr++) {
                    const float4 xv = *(const float4*)&xs[m*WIN + 20*rr + k0];
                    o0[rr] += xv.x*wv0.x + xv.y*wv0.y + xv.z*wv0.z + xv.w*wv0.w;
                    o1[rr] += xv.x*wv1.x + xv.y*wv1.y + xv.z*wv1.z + xv.w*wv1.w;
                }
            }
            #pragma unroll
            for (int rr = 0; rr < RCH; rr++) {
                float v0 = fmaxf(o0[rr], 0.f), v1 = fmaxf(o1[rr], 0.f);
                if (rr >= rcount) { v0 = 0.f; v1 = 0.f; }   // invalid tail rows -> 0
                *(float2*)&cbuf[m*CBS + rr*32 + c0] = make_float2(v0, v1);
            }
        }
        __syncthreads();
        // GEMM: y[m][f] += cbuf[m][i] * W1[row(i)][f]
        for (int il = 0; il < 32*RCH; il += 4) {
            const int rrg = il >> 5;
            const int cg  = il & 31;
            const int r   = r0 + (rrg < rcount ? rrg : 0);   // clamp: cbuf is 0 there
            const size_t rowb = (size_t)cg*RED + r;
            const float2 w0 = *(const float2*)&W1[(rowb        )*HID + f0];
            const float2 w1 = *(const float2*)&W1[(rowb + RED  )*HID + f0];
            const float2 w2 = *(const float2*)&W1[(rowb + 2*RED)*HID + f0];
            const float2 w3 = *(const float2*)&W1[(rowb + 3*RED)*HID + f0];
            #pragma unroll
            for (int k2 = 0; k2 < 8; k2++) {
                const int m = mg + 4*k2;
                const float4 cv = *(const float4*)&cbuf[m*CBS + il];
                a0[k2] += cv.x*w0.x + cv.y*w1.x + cv.z*w2.x + cv.w*w3.x;
                a1[k2] += cv.x*w0.y + cv.y*w1.y + cv.z*w2.y + cv.w*w3.y;
            }
        }
    }
    #pragma unroll
    for (int k2 = 0; k2 < 8; k2++) {
        const int m = mg + 4*k2;
        *(float2*)&z[(size_t)(n0+m)*HID + f0] = make_float2(a0[k2], a1[k2]);
    }
}

// ------------------------------------- GCN aggregate + self + bias + BN + ReLU
// one WG per graph; z read through L1 (graph block = 32KB, resident)
template<int C>
__global__ __launch_bounds__(256) void gcn_post(
    const float* __restrict__ z, const int* __restrict__ ei,
    const float* __restrict__ ew, const float* __restrict__ dinv,
    const float* __restrict__ bias, const float* __restrict__ gam,
    const float* __restrict__ bet, const float* __restrict__ mu,
    const float* __restrict__ var, float* __restrict__ h)
{
    __shared__ float acc[PG*C];
    __shared__ unsigned short sloc[EPG], dloc[EPG];
    __shared__ float nrm[EPG];
    __shared__ float dl[PG];

    const int t  = threadIdx.x;
    const int g  = blockIdx.x;
    const int nb = g*PG;

    if (t < PG) dl[t] = dinv[nb + t];
    for (int i = t; i < PG*C; i += 256) acc[i] = 0.f;
    __syncthreads();
    for (int i = t; i < EPG; i += 256) {
        int e = g*EPG + i;
        int s = ei[e] - nb;
        int d = ei[E_TOT + e] - nb;
        sloc[i] = (unsigned short)s;
        dloc[i] = (unsigned short)d;
        nrm[i]  = dl[s]*ew[e]*dl[d];
    }
    __syncthreads();
    const int f  = t % C;
    const int ep = t / C;
    constexpr int EIP = 256 / C;
    for (int eb = 0; eb < EPG; eb += EIP) {
        int i = eb + ep;
        int s = sloc[i], d = dloc[i];
        atomicAdd(&acc[d*C + f], z[(size_t)(nb+s)*C + f]*nrm[i]);
    }
    __syncthreads();
    for (int i = t; i < PG*C; i += 256) {
        int n = i / C, ff = i - n*C;
        float di = dl[n];
        float v  = acc[i] + z[(size_t)nb*C + i]*(di*di) + bias[ff];
        v = (v - mu[ff]) * (gam[ff]*rsqrtf(var[ff] + 1e-5f)) + bet[ff];
        h[(size_t)nb*C + i] = fmaxf(v, 0.f);
    }
}

// ---------------------------------------------------- node-wise small GEMM
template<int CIN, int COUT>
__global__ __launch_bounds__(256) void gemm_node(
    const float* __restrict__ h, const float* __restrict__ W,
    float* __restrict__ z)
{
    constexpr int FP = COUT/2, TM = 256/FP, MT = 64/TM;
    __shared__ float hl[64*CIN];
    const int t  = threadIdx.x;
    const int n0 = blockIdx.x*64;
    for (int i = t; i < 64*CIN; i += 256) hl[i] = h[(size_t)n0*CIN + i];
    __syncthreads();
    const int f0 = (t % FP)*2;
    const int mb = t / FP;
    float a0[MT], a1[MT];
    #pragma unroll
    for (int k = 0; k < MT; k++) { a0[k] = 0.f; a1[k] = 0.f; }
    for (int kk = 0; kk < CIN; kk += 4) {
        const float2 w0 = *(const float2*)&W[(size_t)(kk+0)*COUT + f0];
        const float2 w1 = *(const float2*)&W[(size_t)(kk+1)*COUT + f0];
        const float2 w2 = *(const float2*)&W[(size_t)(kk+2)*COUT + f0];
        const float2 w3 = *(const float2*)&W[(size_t)(kk+3)*COUT + f0];
        #pragma unroll
        for (int k = 0; k < MT; k++) {
            const float4 hv = *(const float4*)&hl[(mb + TM*k)*CIN + kk];
            a0[k] += hv.x*w0.x + hv.y*w1.x + hv.z*w2.x + hv.w*w3.x;
            a1[k] += hv.x*w0.y + hv.y*w1.y + hv.z*w2.y + hv.w*w3.y;
        }
    }
    #pragma unroll
    for (int k = 0; k < MT; k++) {
        const int m = mb + TM*k;
        *(float2*)&z[(size_t)(n0+m)*COUT + f0] = make_float2(a0[k], a1[k]);
    }
}

// ------------------------------------------------- mean-pool + FC + log_softmax
__global__ __launch_bounds__(64) void pool_fc(
    const float* __restrict__ h3, const float* __restrict__ fcw,
    const float* __restrict__ fcb, float* __restrict__ out)
{
    __shared__ float ps[OUT3];
    const int g = blockIdx.x, t = threadIdx.x;
    float s = 0.f;
    for (int n = 0; n < PG; n++) s += h3[(size_t)(g*PG + n)*OUT3 + t];
    ps[t] = s * (1.0f/PG);
    __syncthreads();
    if (t == 0) {
        float l0 = fcb[0], l1 = fcb[1];
        for (int f = 0; f < OUT3; f++) { l0 += ps[f]*fcw[f*2]; l1 += ps[f]*fcw[f*2+1]; }
        float m   = fmaxf(l0, l1);
        float lse = m + logf(expf(l0 - m) + expf(l1 - m));
        out[g*2 + 0] = l0 - lse;
        out[g*2 + 1] = l1 - lse;
    }
}

// ---------------------------------------------------------------- launch
extern "C" void kernel_launch(void* const* d_in, const int* in_sizes, int n_in,
                              void* d_out, int out_size, void* d_ws, size_t ws_size,
                              hipStream_t stream) {
    const float* x   = (const float*)d_in[0];
    const int*   ei  = (const int*)  d_in[1];
    const float* ew  = (const float*)d_in[2];
    // d_in[3] = batch (implicit: 64-node blocks)
    const float* cw  = (const float*)d_in[4];
    const float* cb  = (const float*)d_in[5];
    const float* W1  = (const float*)d_in[6];
    const float* b1  = (const float*)d_in[7];
    const float* W2  = (const float*)d_in[8];
    const float* b2  = (const float*)d_in[9];
    const float* W3  = (const float*)d_in[10];
    const float* b3  = (const float*)d_in[11];
    const float* g1  = (const float*)d_in[12];
    const float* be1 = (const float*)d_in[13];
    const float* m1  = (const float*)d_in[14];
    const float* v1  = (const float*)d_in[15];
    const float* g2  = (const float*)d_in[16];
    const float* be2 = (const float*)d_in[17];
    const float* m2  = (const float*)d_in[18];
    const float* v2  = (const float*)d_in[19];
    const float* g3  = (const float*)d_in[20];
    const float* be3 = (const float*)d_in[21];
    const float* m3  = (const float*)d_in[22];
    const float* v3  = (const float*)d_in[23];
    const float* fcw = (const float*)d_in[24];
    const float* fcb = (const float*)d_in[25];
    float* out = (float*)d_out;

    float* z    = (float*)d_ws;              // N*128
    float* h    = z + (size_t)N_NODES*HID;   // N*128
    float* deg  = h + (size_t)N_NODES*HID;   // N
    float* dinv = deg + N_NODES;             // N

    deg_init<<<N_NODES/256, 256, 0, stream>>>(deg);
    deg_acc <<<E_TOT/256,   256, 0, stream>>>(ei, ew, deg);
    dinv_k  <<<N_NODES/256, 256, 0, stream>>>(deg, dinv);

    conv_gemm1<<<N_NODES/32, 256, 0, stream>>>(x, cw, cb, W1, z);
    gcn_post<HID><<<NG, 256, 0, stream>>>(z, ei, ew, dinv, b1, g1, be1, m1, v1, h);
    gemm_node<HID, HID><<<N_NODES/64, 256, 0, stream>>>(h, W2, z);
    gcn_post<HID><<<NG, 256, 0, stream>>>(z, ei, ew, dinv, b2, g2, be2, m2, v2, h);
    gemm_node<HID, OUT3><<<N_NODES/64, 256, 0, stream>>>(h, W3, z);
    gcn_post<OUT3><<<NG, 256, 0, stream>>>(z, ei, ew, dinv, b3, g3, be3, m3, v3, h);
    pool_fc<<<NG, 64, 0, stream>>>(h, fcw, fcb, out);
}

// Round 2
// 753.173 us; speedup vs baseline: 4.4954x; 4.4954x over previous
//
#include <hip/hip_runtime.h>
#include <math.h>

typedef float f32x4 __attribute__((ext_vector_type(4)));
typedef short bf16x8 __attribute__((ext_vector_type(8)));

constexpr int N_NODES = 32768;
constexpr int LEN     = 3000;
constexpr int HID     = 128;
constexpr int OUT3    = 64;
constexpr int E_TOT   = 32768*16;
constexpr int PG      = 64;
constexpr int EPG     = 1024;
constexpr int NG      = 512;
constexpr int NCHUNK  = 25;          // 25 chunks x 6 r-positions (last has 2 valid)

// ---- bf16 helpers (RNE) ----
__device__ __forceinline__ short bf1(float a) {
    unsigned u = __float_as_uint(a);
    return (short)((u + 0x7fff + ((u >> 16) & 1)) >> 16);
}
__device__ __forceinline__ unsigned bfpk2(float a, float b) {
    unsigned ua = __float_as_uint(a); ua = (ua + 0x7fff + ((ua >> 16) & 1)) >> 16;
    unsigned ub = __float_as_uint(b); ub = (ub + 0x7fff + ((ub >> 16) & 1)) >> 16;
    return (ua & 0xffffu) | (ub << 16);
}
__device__ __forceinline__ unsigned long long pk4(float a, float b, float c, float d) {
    return (unsigned long long)bfpk2(a, b) | ((unsigned long long)bfpk2(c, d) << 32);
}

// ================= pre-pack conv weights into A-fragment order ==============
// wPf[(Mt*4+ks)*64 + lane][8]: A[c][k], c = Mt*16+(lane&15), k = ks*32+(lane>>4)*8+j
__global__ void pack_w(const float* __restrict__ cw, short* __restrict__ wPf) {
    int tid = blockIdx.x * 256 + threadIdx.x;
    if (tid >= 512) return;
    int lane = tid & 63, i = tid >> 6;
    int Mt = i >> 2, ks = i & 3;
    int c  = Mt * 16 + (lane & 15);
    int kb = ks * 32 + (lane >> 4) * 8;
    bf16x8 v;
    #pragma unroll
    for (int j = 0; j < 8; j++) {
        int k = kb + j;
        v[j] = (k < 100) ? bf1(cw[c * 100 + k]) : (short)0;
    }
    *(bf16x8*)(wPf + tid * 8) = v;
}

// ============== pre-pack W1 into B-fragment order (per chunk) ===============
// flat = (chunk*8 + Nt)*6 + ks ; lane ; j : B[kl][n], kl = ks*32 + (lane>>4)*8 + j
// -> rr = ks, c = (lane>>4)*8+j, k_global = c*146 + chunk*6 + rr, n = Nt*16+(lane&15)
__global__ void pack_w1(const float* __restrict__ W1, short* __restrict__ w1f) {
    int tid = blockIdx.x * 256 + threadIdx.x;     // < 76800
    if (tid >= 76800) return;
    int lane  = tid & 63;
    int rest  = tid >> 6;                          // < 1200
    int ks    = rest % 6;
    int rest2 = rest / 6;                          // < 200
    int Nt    = rest2 & 7, chunk = rest2 >> 3;
    int r  = chunk * 6 + ks;
    int n  = Nt * 16 + (lane & 15);
    int cb = (lane >> 4) * 8;
    bf16x8 v;
    #pragma unroll
    for (int j = 0; j < 8; j++) {
        int c = cb + j;
        v[j] = (r < 146) ? bf1(W1[(c * 146 + r) * 128 + n]) : (short)0;
    }
    *(bf16x8*)(w1f + tid * 8) = v;
}

// ========== fused conv1d+relu+GEMM1, bf16 MFMA, x ring buffer ==============
// 64 nodes/WG. Per chunk: conv computed as C^T (A = weights [32 x 128k],
// B = x-ring [128k x 384 (node,rr)]) -> cbuf in GEMM1-A layout -> GEMM1 MFMA
// with W1 B-frags streamed global->VGPR. LDS 58.9KB -> 2 WG/CU.
__global__ __launch_bounds__(256, 2) void conv_gemm1_mfma(
    const float* __restrict__ x, const short* __restrict__ wPf,
    const float* __restrict__ cbv, const short* __restrict__ w1f,
    float* __restrict__ z)
{
    __shared__ short xs[64 * 264];    // ring: 256 logical elems/node, stride 264
    __shared__ short cbuf[64 * 196];  // [node][kl=rr*32+c], stride 196

    const int t    = threadIdx.x;
    const int lane = t & 63;
    const int wv   = t >> 6;
    const int l15  = lane & 15;
    const int q    = lane >> 4;
    const int n0   = blockIdx.x * 64;

    // conv A-frags (weights, constant) + per-lane conv bias rows
    bf16x8 wA[8];
    #pragma unroll
    for (int i = 0; i < 8; i++)
        wA[i] = *(const bf16x8*)(wPf + (i * 64 + lane) * 8);
    float cbr[8];                      // [Mt*4+reg] : c = Mt*16 + q*4 + reg
    #pragma unroll
    for (int i = 0; i < 8; i++)
        cbr[i] = cbv[(i >> 2) * 16 + q * 4 + (i & 3)];

    f32x4 acc[4][2];                   // [node Mt][gemm Nt-pair]
    #pragma unroll
    for (int a = 0; a < 4; a++) { acc[a][0] = (f32x4)0.0f; acc[a][1] = (f32x4)0.0f; }

    const int NtG0 = wv * 2;           // this wave's 2 gemm N-tiles
    const int NtC0 = wv * 6;           // this wave's 6 conv N-tiles

    #pragma unroll 1
    for (int c = 0; c < NCHUNK; c++) {
        const int r0 = c * 6;
        const int rcount = (146 - r0 < 6) ? (146 - r0) : 6;

        // prefetch this chunk's W1 B-frags (global, no LDS dependency)
        bf16x8 wB[12];                 // [nt2*6 + ks]
        #pragma unroll
        for (int u = 0; u < 12; u++) {
            int nt2 = u / 6, ks = u - nt2 * 6;
            int flat = (c * 8 + NtG0 + nt2) * 6 + ks;
            wB[u] = *(const bf16x8*)(w1f + (flat * 64 + lane) * 8);
        }

        __syncthreads();   // prev chunk's readers of xs/cbuf are done
        // ---- stage new x into ring (fp32 -> bf16) ----
        if (c == 0) {
            for (int u = t; u < 64 * 60; u += 256) {
                int node = u / 60, j = u - node * 60;
                int e = j * 4;
                const float4 vx = *(const float4*)&x[(size_t)(n0 + node) * LEN + e];
                *(unsigned long long*)&xs[node * 264 + (e & 255)] = pk4(vx.x, vx.y, vx.z, vx.w);
            }
        } else {
            const int L = 120 * c + 120;
            for (int u = t; u < 64 * 30; u += 256) {
                int node = u / 30, j = u - node * 30;
                int e  = L + j * 4;
                int ge = (e > 2996) ? 2996 : e;    // clamp; values masked later
                const float4 vx = *(const float4*)&x[(size_t)(n0 + node) * LEN + ge];
                *(unsigned long long*)&xs[node * 264 + (e & 255)] = pk4(vx.x, vx.y, vx.z, vx.w);
            }
        }
        __syncthreads();

        // ---- conv via MFMA (C^T): D[c'][n''], n'' = node*6+rr ----
        for (int ntc = 0; ntc < 6; ntc++) {
            int nn = (NtC0 + ntc) * 16 + l15;
            int m  = nn / 6;
            int rr = nn - m * 6;
            int eb = 20 * (r0 + rr) + q * 8;
            f32x4 ca0 = (f32x4)0.0f, ca1 = (f32x4)0.0f;
            #pragma unroll
            for (int ks = 0; ks < 4; ks++) {
                int e0 = eb + ks * 32;
                bf16x8 bx;
                ((unsigned long long*)&bx)[0] = *(const unsigned long long*)&xs[m * 264 + (e0 & 255)];
                ((unsigned long long*)&bx)[1] = *(const unsigned long long*)&xs[m * 264 + ((e0 + 4) & 255)];
                ca0 = __builtin_amdgcn_mfma_f32_16x16x32_bf16(wA[ks],     bx, ca0, 0, 0, 0);
                ca1 = __builtin_amdgcn_mfma_f32_16x16x32_bf16(wA[4 + ks], bx, ca1, 0, 0, 0);
            }
            const bool valid = (rr < rcount);
            const int wb = m * 196 + rr * 32 + q * 4;
            float v0 = valid ? fmaxf(ca0[0] + cbr[0], 0.f) : 0.f;
            float v1 = valid ? fmaxf(ca0[1] + cbr[1], 0.f) : 0.f;
            float v2 = valid ? fmaxf(ca0[2] + cbr[2], 0.f) : 0.f;
            float v3 = valid ? fmaxf(ca0[3] + cbr[3], 0.f) : 0.f;
            *(unsigned long long*)&cbuf[wb] = pk4(v0, v1, v2, v3);
            v0 = valid ? fmaxf(ca1[0] + cbr[4], 0.f) : 0.f;
            v1 = valid ? fmaxf(ca1[1] + cbr[5], 0.f) : 0.f;
            v2 = valid ? fmaxf(ca1[2] + cbr[6], 0.f) : 0.f;
            v3 = valid ? fmaxf(ca1[3] + cbr[7], 0.f) : 0.f;
            *(unsigned long long*)&cbuf[wb + 16] = pk4(v0, v1, v2, v3);
        }
        __syncthreads();

        // ---- GEMM1: acc[node][f] += cbuf * W1frags ----
        #pragma unroll
        for (int ks = 0; ks < 6; ks++) {
            bf16x8 af[4];
            #pragma unroll
            for (int mt = 0; mt < 4; mt++) {
                int ad = (mt * 16 + l15) * 196 + ks * 32 + q * 8;
                ((unsigned long long*)&af[mt])[0] = *(const unsigned long long*)&cbuf[ad];
                ((unsigned long long*)&af[mt])[1] = *(const unsigned long long*)&cbuf[ad + 4];
            }
            #pragma unroll
            for (int mt = 0; mt < 4; mt++) {
                acc[mt][0] = __builtin_amdgcn_mfma_f32_16x16x32_bf16(af[mt], wB[ks],     acc[mt][0], 0, 0, 0);
                acc[mt][1] = __builtin_amdgcn_mfma_f32_16x16x32_bf16(af[mt], wB[6 + ks], acc[mt][1], 0, 0, 0);
            }
        }
    }

    // epilogue: z[node][f] fp32
    #pragma unroll
    for (int mt = 0; mt < 4; mt++)
        #pragma unroll
        for (int nt2 = 0; nt2 < 2; nt2++)
            #pragma unroll
            for (int reg = 0; reg < 4; reg++) {
                int node = n0 + mt * 16 + q * 4 + reg;
                int f    = (NtG0 + nt2) * 16 + l15;
                z[(size_t)node * HID + f] = acc[mt][nt2][reg];
            }
}

// ====== per-graph fused: deg + dense-A + 3x(GCN agg+BN+ReLU) + GEMMs + pool+FC
__global__ __launch_bounds__(256) void graph_block(
    const float* __restrict__ z, const int* __restrict__ ei,
    const float* __restrict__ ew,
    const float* __restrict__ b1, const float* __restrict__ g1, const float* __restrict__ be1,
    const float* __restrict__ m1, const float* __restrict__ v1,
    const float* __restrict__ W2,
    const float* __restrict__ b2, const float* __restrict__ g2, const float* __restrict__ be2,
    const float* __restrict__ m2, const float* __restrict__ v2,
    const float* __restrict__ W3,
    const float* __restrict__ b3, const float* __restrict__ g3, const float* __restrict__ be3,
    const float* __restrict__ m3, const float* __restrict__ v3,
    const float* __restrict__ fcw, const float* __restrict__ fcb,
    float* __restrict__ out)
{
    __shared__ float At[64 * 68];     // [src][dst], padded
    __shared__ float buf[8704];       // union: zb[64][128] / hT[128][68] / zb64[64][64]
    __shared__ float dl[64];
    __shared__ float ps4[256];
    __shared__ float pooled[64];

    const int t  = threadIdx.x;
    const int g  = blockIdx.x;
    const int nb = g * PG;

    for (int i = t; i < 64 * 68; i += 256) At[i] = 0.f;
    if (t < 64) dl[t] = 0.f;
    __syncthreads();
    for (int i = t; i < EPG; i += 256) {
        int e = g * EPG + i;
        atomicAdd(&dl[ei[E_TOT + e] - nb], ew[e]);
    }
    __syncthreads();
    if (t < 64) dl[t] = rsqrtf(dl[t] + 1.0f);
    __syncthreads();
    for (int i = t; i < EPG; i += 256) {
        int e = g * EPG + i;
        int s = ei[e] - nb, d = ei[E_TOT + e] - nb;
        atomicAdd(&At[s * 68 + d], dl[s] * ew[e] * dl[d]);
    }
    if (t < 64) atomicAdd(&At[t * 68 + t], dl[t] * dl[t]);   // self-loop
    for (int i = t; i < 64 * HID; i += 256) buf[i] = z[(size_t)nb * HID + i];
    __syncthreads();

    const int f   = t & 127;
    const int ng  = t >> 7;
    const int n0  = ng * 32;
    const int f3  = t & 63;
    const int ng3 = t >> 6;
    const int n03 = ng3 * 16;

    float hreg[32];

#define LAYER128(BB, GG, BE, MM, VV)                                          \
    {                                                                         \
        float sc = GG[f] * rsqrtf(VV[f] + 1e-5f);                             \
        float mu = MM[f], bt = BE[f], bb = BB[f];                             \
        float a[32];                                                          \
        _Pragma("unroll")                                                     \
        for (int i = 0; i < 32; i++) a[i] = 0.f;                              \
        _Pragma("unroll 2")                                                   \
        for (int s = 0; s < 64; s++) {                                        \
            float zv = buf[s * 128 + f];                                      \
            _Pragma("unroll")                                                 \
            for (int qq = 0; qq < 8; qq++) {                                  \
                float4 a4 = *(const float4*)&At[s * 68 + n0 + qq * 4];        \
                a[qq*4+0] += a4.x * zv; a[qq*4+1] += a4.y * zv;               \
                a[qq*4+2] += a4.z * zv; a[qq*4+3] += a4.w * zv;               \
            }                                                                 \
        }                                                                     \
        _Pragma("unroll")                                                     \
        for (int i = 0; i < 32; i++)                                          \
            hreg[i] = fmaxf((a[i] + bb - mu) * sc + bt, 0.f);                 \
    }                                                                         \
    __syncthreads();                                                          \
    _Pragma("unroll")                                                         \
    for (int qq = 0; qq < 8; qq++)                                            \
        *(float4*)&buf[f * 68 + n0 + qq * 4] =                                \
            make_float4(hreg[qq*4], hreg[qq*4+1], hreg[qq*4+2], hreg[qq*4+3]);\
    __syncthreads();

#define GEMM128(WPTR)                                                         \
    {                                                                         \
        float a[32];                                                          \
        _Pragma("unroll")                                                     \
        for (int i = 0; i < 32; i++) a[i] = 0.f;                              \
        _Pragma("unroll 2")                                                   \
        for (int k = 0; k < 128; k++) {                                       \
            float wvv = WPTR[k * 128 + f];                                    \
            _Pragma("unroll")                                                 \
            for (int qq = 0; qq < 8; qq++) {                                  \
                float4 h4 = *(const float4*)&buf[k * 68 + n0 + qq * 4];       \
                a[qq*4+0] += h4.x * wvv; a[qq*4+1] += h4.y * wvv;             \
                a[qq*4+2] += h4.z * wvv; a[qq*4+3] += h4.w * wvv;             \
            }                                                                 \
        }                                                                     \
        __syncthreads();                                                      \
        _Pragma("unroll")                                                     \
        for (int i = 0; i < 32; i++) buf[(n0 + i) * 128 + f] = a[i];          \
        __syncthreads();                                                      \
    }

    LAYER128(b1, g1, be1, m1, v1)      // layer 1 -> hT in buf
    GEMM128(W2)                        // z2 -> zb in buf
    LAYER128(b2, g2, be2, m2, v2)      // layer 2 -> hT in buf

    // GEMM3: z3[n][f3] (OUT3=64)
    {
        float a[16];
        #pragma unroll
        for (int i = 0; i < 16; i++) a[i] = 0.f;
        #pragma unroll 2
        for (int k = 0; k < 128; k++) {
            float wvv = W3[k * 64 + f3];
            #pragma unroll
            for (int qq = 0; qq < 4; qq++) {
                float4 h4 = *(const float4*)&buf[k * 68 + n03 + qq * 4];
                a[qq*4+0] += h4.x * wvv; a[qq*4+1] += h4.y * wvv;
                a[qq*4+2] += h4.z * wvv; a[qq*4+3] += h4.w * wvv;
            }
        }
        __syncthreads();
        #pragma unroll
        for (int i = 0; i < 16; i++) buf[(n03 + i) * 64 + f3] = a[i];
        __syncthreads();
    }

    // layer 3 agg + BN + ReLU + pool partial
    {
        float sc = g3[f3] * rsqrtf(v3[f3] + 1e-5f);
        float mu = m3[f3], bt = be3[f3], bb = b3[f3];
        float a[16];
        #pragma unroll
        for (int i = 0; i < 16; i++) a[i] = 0.f;
        #pragma unroll 2
        for (int s = 0; s < 64; s++) {
            float zv = buf[s * 64 + f3];
            #pragma unroll
            for (int qq = 0; qq < 4; qq++) {
                float4 a4 = *(const float4*)&At[s * 68 + n03 + qq * 4];
                a[qq*4+0] += a4.x * zv; a[qq*4+1] += a4.y * zv;
                a[qq*4+2] += a4.z * zv; a[qq*4+3] += a4.w * zv;
            }
        }
        float psum = 0.f;
        #pragma unroll
        for (int i = 0; i < 16; i++)
            psum += fmaxf((a[i] + bb - mu) * sc + bt, 0.f);
        ps4[ng3 * 64 + f3] = psum;
    }
    __syncthreads();
    if (t < 64) pooled[t] = (ps4[t] + ps4[64 + t] + ps4[128 + t] + ps4[192 + t]) * (1.f / 64.f);
    __syncthreads();
    if (t == 0) {
        float l0 = fcb[0], l1 = fcb[1];
        for (int ff = 0; ff < 64; ff++) { l0 += pooled[ff] * fcw[ff * 2]; l1 += pooled[ff] * fcw[ff * 2 + 1]; }
        float mx  = fmaxf(l0, l1);
        float lse = mx + logf(expf(l0 - mx) + expf(l1 - mx));
        out[g * 2 + 0] = l0 - lse;
        out[g * 2 + 1] = l1 - lse;
    }
#undef LAYER128
#undef GEMM128
}

// ---------------------------------------------------------------- launch
extern "C" void kernel_launch(void* const* d_in, const int* in_sizes, int n_in,
                              void* d_out, int out_size, void* d_ws, size_t ws_size,
                              hipStream_t stream) {
    const float* x   = (const float*)d_in[0];
    const int*   ei  = (const int*)  d_in[1];
    const float* ew  = (const float*)d_in[2];
    const float* cw  = (const float*)d_in[4];
    const float* cb  = (const float*)d_in[5];
    const float* W1  = (const float*)d_in[6];
    const float* b1  = (const float*)d_in[7];
    const float* W2  = (const float*)d_in[8];
    const float* b2  = (const float*)d_in[9];
    const float* W3  = (const float*)d_in[10];
    const float* b3  = (const float*)d_in[11];
    const float* g1  = (const float*)d_in[12];
    const float* be1 = (const float*)d_in[13];
    const float* m1  = (const float*)d_in[14];
    const float* v1  = (const float*)d_in[15];
    const float* g2  = (const float*)d_in[16];
    const float* be2 = (const float*)d_in[17];
    const float* m2  = (const float*)d_in[18];
    const float* v2  = (const float*)d_in[19];
    const float* g3  = (const float*)d_in[20];
    const float* be3 = (const float*)d_in[21];
    const float* m3  = (const float*)d_in[22];
    const float* v3  = (const float*)d_in[23];
    const float* fcw = (const float*)d_in[24];
    const float* fcb = (const float*)d_in[25];
    float* out = (float*)d_out;

    float* z   = (float*)d_ws;                            // 16,777,216 B
    short* wPf = (short*)((char*)d_ws + 16777216);        // 8,192 B
    short* w1f = (short*)((char*)d_ws + 16785408);        // 1,228,800 B

    pack_w  <<<2,   256, 0, stream>>>(cw, wPf);
    pack_w1 <<<300, 256, 0, stream>>>(W1, w1f);
    conv_gemm1_mfma<<<NG, 256, 0, stream>>>(x, wPf, cb, w1f, z);
    graph_block<<<NG, 256, 0, stream>>>(z, ei, ew,
        b1, g1, be1, m1, v1, W2,
        b2, g2, be2, m2, v2, W3,
        b3, g3, be3, m3, v3, fcw, fcb, out);
}

// Round 3
// 686.097 us; speedup vs baseline: 4.9349x; 1.0978x over previous
//
#include <hip/hip_runtime.h>
#include <math.h>

typedef float f32x4 __attribute__((ext_vector_type(4)));
typedef short bf16x8 __attribute__((ext_vector_type(8)));
typedef unsigned int u32;
typedef unsigned long long u64;

constexpr int N_NODES = 32768;
constexpr int LEN     = 3000;
constexpr int HID     = 128;
constexpr int OUT3    = 64;
constexpr int E_TOT   = 32768*16;
constexpr int PG      = 64;
constexpr int EPG     = 1024;
constexpr int NG      = 512;
constexpr int NCHUNK  = 25;          // 25 chunks x 6 r-positions (last has 2 valid)
constexpr int XS_S    = 260;         // ring stride (shorts); 130 dw -> mild conflicts, 8B aligned rows
constexpr int CBS     = 196;         // cbuf stride (shorts); 392 B, 8B aligned rows

// ---- bf16 helpers ----
__device__ __forceinline__ short bf1(float a) {          // RNE (cold pack kernels)
    unsigned u = __float_as_uint(a);
    return (short)((u + 0x7fff + ((u >> 16) & 1)) >> 16);
}
__device__ __forceinline__ u32 pk2(float lo, float hi) { // round-half-up (hot path, 3 VALU)
    u32 ua = __float_as_uint(lo) + 0x8000u;
    u32 ub = __float_as_uint(hi) + 0x8000u;
    return (ua >> 16) | (ub & 0xffff0000u);
}

// ================= pre-pack conv weights into A-fragment order ==============
// wPf[(Mt*4+ks)*64 + lane][8]: A[c][k], c = Mt*16+(lane&15), k = ks*32+(lane>>4)*8+j
__global__ void pack_w(const float* __restrict__ cw, short* __restrict__ wPf) {
    int tid = blockIdx.x * 256 + threadIdx.x;
    if (tid >= 512) return;
    int lane = tid & 63, i = tid >> 6;
    int Mt = i >> 2, ks = i & 3;
    int c  = Mt * 16 + (lane & 15);
    int kb = ks * 32 + (lane >> 4) * 8;
    bf16x8 v;
    #pragma unroll
    for (int j = 0; j < 8; j++) {
        int k = kb + j;
        v[j] = (k < 100) ? bf1(cw[c * 100 + k]) : (short)0;
    }
    *(bf16x8*)(wPf + tid * 8) = v;
}

// ============== pre-pack W1 into B-fragment order (per chunk) ===============
__global__ void pack_w1(const float* __restrict__ W1, short* __restrict__ w1f) {
    int tid = blockIdx.x * 256 + threadIdx.x;     // < 76800
    if (tid >= 76800) return;
    int lane  = tid & 63;
    int rest  = tid >> 6;                          // < 1200
    int ks    = rest % 6;
    int rest2 = rest / 6;                          // < 200
    int Nt    = rest2 & 7, chunk = rest2 >> 3;
    int r  = chunk * 6 + ks;
    int n  = Nt * 16 + (lane & 15);
    int cb = (lane >> 4) * 8;
    bf16x8 v;
    #pragma unroll
    for (int j = 0; j < 8; j++) {
        int c = cb + j;
        v[j] = (r < 146) ? bf1(W1[(c * 146 + r) * 128 + n]) : (short)0;
    }
    *(bf16x8*)(w1f + tid * 8) = v;
}

// ========== fused conv1d+relu+GEMM1, bf16 MFMA, wave-private x ring =========
// 64 nodes/WG, 16 nodes/wave. rr-major conv (B n-index = node = lane&15):
// xs is wave-private -> no staging barriers; x software-pipelined via VGPRs.
// Only cbuf needs 2 barriers/chunk. LDS 58.4KB -> 2 WG/CU.
__global__ __launch_bounds__(256, 2) void conv_gemm1_mfma(
    const float* __restrict__ x, const short* __restrict__ wPf,
    const float* __restrict__ cbv, const short* __restrict__ w1f,
    float* __restrict__ z)
{
    __shared__ short xs[64 * XS_S];    // ring: 256 logical elems/node
    __shared__ short cbuf[64 * CBS];   // [node][kl = rr*32 + c]

    const int t     = threadIdx.x;
    const int lane  = t & 63;
    const int wv    = t >> 6;
    const int l15   = lane & 15;
    const int q     = lane >> 4;
    const int n0    = blockIdx.x * 64;
    const int j4    = lane & 3;
    const int nodeS = wv * 16 + (lane >> 2);   // staging node (4 lanes/node)
    const int nodeC = wv * 16 + l15;           // conv node

    // conv A-frags (weights) + per-lane conv bias rows
    bf16x8 wA[8];
    #pragma unroll
    for (int i = 0; i < 8; i++)
        wA[i] = *(const bf16x8*)(wPf + (i * 64 + lane) * 8);
    float cbr[8];                      // c = (i>>2)*16 + q*4 + (i&3)
    #pragma unroll
    for (int i = 0; i < 8; i++)
        cbr[i] = cbv[(i >> 2) * 16 + q * 4 + (i & 3)];

    f32x4 acc[4][2];                   // [node mt][gemm Nt-pair]
    #pragma unroll
    for (int a = 0; a < 4; a++) { acc[a][0] = (f32x4)0.0f; acc[a][1] = (f32x4)0.0f; }

    const int NtG0 = wv * 2;           // this wave's 2 gemm N-tiles
    const float* xpS = x + (size_t)(n0 + nodeS) * LEN;
    short* xrow = xs + nodeS * XS_S;

    // ---- initial stage: elements [0,208) for this wave's nodes (wave-private) ----
    {
        float4 v[13];
        #pragma unroll
        for (int it = 0; it < 13; it++)
            v[it] = *(const float4*)(xpS + (j4 + 4 * it) * 4);
        #pragma unroll
        for (int it = 0; it < 13; it++) {
            int e = (j4 + 4 * it) * 4;
            *(uint2*)&xrow[e] = make_uint2(pk2(v[it].x, v[it].y), pk2(v[it].z, v[it].w));
        }
    }

    #pragma unroll 1
    for (int c = 0; c < NCHUNK; c++) {
        const int r0 = c * 6;
        const int rcount = (146 - r0 < 6) ? (146 - r0) : 6;

        // prefetch next chunk's new x range [120c+200, 120c+320) into VGPRs
        float4 xn[8];
        if (c < NCHUNK - 1) {
            const int ebase = 120 * c + 200;
            #pragma unroll
            for (int it = 0; it < 8; it++) {
                int e  = ebase + (j4 + 4 * it) * 4;
                int ge = e > 2996 ? 2996 : e;          // clamp; garbage lands in masked/overwritten slots
                xn[it] = *(const float4*)(xpS + ge);
            }
        }
        // prefetch this chunk's W1 B-frags (global; consumed after barrier #2)
        bf16x8 wB[12];                 // [nt2*6 + ks]
        #pragma unroll
        for (int u = 0; u < 12; u++)
            wB[u] = *(const bf16x8*)(w1f + ((c * 48 + NtG0 * 6 + u) * 64 + lane) * 8);

        __syncthreads();               // barrier #1: prev GEMM done reading cbuf

        // ---- conv via MFMA: D[c'][node], node = wave's 16 nodes ----
        const short* xr = xs + nodeC * XS_S;
        #pragma unroll
        for (int rr = 0; rr < 6; rr++) {
            const int eb = 20 * (r0 + rr) + 8 * q;
            f32x4 ca0 = (f32x4)0.0f, ca1 = (f32x4)0.0f;
            #pragma unroll
            for (int ks = 0; ks < 4; ks++) {
                int e0 = eb + 32 * ks;
                bf16x8 bx;
                *(u64*)&bx       = *(const u64*)&xr[e0 & 255];
                *((u64*)&bx + 1) = *(const u64*)&xr[(e0 + 4) & 255];
                ca0 = __builtin_amdgcn_mfma_f32_16x16x32_bf16(wA[ks],     bx, ca0, 0, 0, 0);
                ca1 = __builtin_amdgcn_mfma_f32_16x16x32_bf16(wA[4 + ks], bx, ca1, 0, 0, 0);
            }
            short* cw_ = cbuf + nodeC * CBS + rr * 32 + q * 4;
            if (rr < rcount) {
                u32 p0 = pk2(fmaxf(ca0[0] + cbr[0], 0.f), fmaxf(ca0[1] + cbr[1], 0.f));
                u32 p1 = pk2(fmaxf(ca0[2] + cbr[2], 0.f), fmaxf(ca0[3] + cbr[3], 0.f));
                *(uint2*)cw_ = make_uint2(p0, p1);
                p0 = pk2(fmaxf(ca1[0] + cbr[4], 0.f), fmaxf(ca1[1] + cbr[5], 0.f));
                p1 = pk2(fmaxf(ca1[2] + cbr[6], 0.f), fmaxf(ca1[3] + cbr[7], 0.f));
                *(uint2*)(cw_ + 16) = make_uint2(p0, p1);
            } else {
                *(uint2*)cw_        = make_uint2(0u, 0u);
                *(uint2*)(cw_ + 16) = make_uint2(0u, 0u);
            }
        }

        // ---- write prefetched x into ring (wave-private; after own conv reads) ----
        if (c < NCHUNK - 1) {
            const int ebase = 120 * c + 200;
            #pragma unroll
            for (int it = 0; it < 8; it++) {
                int e = ebase + (j4 + 4 * it) * 4;
                *(uint2*)&xrow[e & 255] = make_uint2(pk2(xn[it].x, xn[it].y), pk2(xn[it].z, xn[it].w));
            }
        }

        __syncthreads();               // barrier #2: cbuf ready

        // ---- GEMM1: acc[node][f] += cbuf * W1frags ----
        #pragma unroll
        for (int ks = 0; ks < 6; ks++) {
            bf16x8 af[4];
            #pragma unroll
            for (int mt = 0; mt < 4; mt++) {
                const short* ap = cbuf + (mt * 16 + l15) * CBS + ks * 32 + q * 8;
                *(u64*)&af[mt]       = *(const u64*)ap;
                *((u64*)&af[mt] + 1) = *(const u64*)(ap + 4);
            }
            #pragma unroll
            for (int mt = 0; mt < 4; mt++) {
                acc[mt][0] = __builtin_amdgcn_mfma_f32_16x16x32_bf16(af[mt], wB[ks],     acc[mt][0], 0, 0, 0);
                acc[mt][1] = __builtin_amdgcn_mfma_f32_16x16x32_bf16(af[mt], wB[6 + ks], acc[mt][1], 0, 0, 0);
            }
        }
    }

    // epilogue: z[node][f] fp32
    #pragma unroll
    for (int mt = 0; mt < 4; mt++)
        #pragma unroll
        for (int nt2 = 0; nt2 < 2; nt2++)
            #pragma unroll
            for (int reg = 0; reg < 4; reg++) {
                int node = n0 + mt * 16 + q * 4 + reg;
                int f    = (NtG0 + nt2) * 16 + l15;
                z[(size_t)node * HID + f] = acc[mt][nt2][reg];
            }
}

// ====== per-graph fused: deg + dense-A + 3x(GCN agg+BN+ReLU) + GEMMs + pool+FC
__global__ __launch_bounds__(256) void graph_block(
    const float* __restrict__ z, const int* __restrict__ ei,
    const float* __restrict__ ew,
    const float* __restrict__ b1, const float* __restrict__ g1, const float* __restrict__ be1,
    const float* __restrict__ m1, const float* __restrict__ v1,
    const float* __restrict__ W2,
    const float* __restrict__ b2, const float* __restrict__ g2, const float* __restrict__ be2,
    const float* __restrict__ m2, const float* __restrict__ v2,
    const float* __restrict__ W3,
    const float* __restrict__ b3, const float* __restrict__ g3, const float* __restrict__ be3,
    const float* __restrict__ m3, const float* __restrict__ v3,
    const float* __restrict__ fcw, const float* __restrict__ fcb,
    float* __restrict__ out)
{
    __shared__ float At[64 * 68];     // [src][dst], padded
    __shared__ float buf[8704];       // union: zb[64][128] / hT[128][68] / zb64[64][64]
    __shared__ float dl[64];
    __shared__ float ps4[256];
    __shared__ float pooled[64];

    const int t  = threadIdx.x;
    const int g  = blockIdx.x;
    const int nb = g * PG;

    for (int i = t; i < 64 * 68; i += 256) At[i] = 0.f;
    if (t < 64) dl[t] = 0.f;
    __syncthreads();
    for (int i = t; i < EPG; i += 256) {
        int e = g * EPG + i;
        atomicAdd(&dl[ei[E_TOT + e] - nb], ew[e]);
    }
    __syncthreads();
    if (t < 64) dl[t] = rsqrtf(dl[t] + 1.0f);
    __syncthreads();
    for (int i = t; i < EPG; i += 256) {
        int e = g * EPG + i;
        int s = ei[e] - nb, d = ei[E_TOT + e] - nb;
        atomicAdd(&At[s * 68 + d], dl[s] * ew[e] * dl[d]);
    }
    if (t < 64) atomicAdd(&At[t * 68 + t], dl[t] * dl[t]);   // self-loop
    for (int i = t; i < 64 * HID; i += 256) buf[i] = z[(size_t)nb * HID + i];
    __syncthreads();

    const int f   = t & 127;
    const int ng  = t >> 7;
    const int n0  = ng * 32;
    const int f3  = t & 63;
    const int ng3 = t >> 6;
    const int n03 = ng3 * 16;

    float hreg[32];

#define LAYER128(BB, GG, BE, MM, VV)                                          \
    {                                                                         \
        float sc = GG[f] * rsqrtf(VV[f] + 1e-5f);                             \
        float mu = MM[f], bt = BE[f], bb = BB[f];                             \
        float a[32];                                                          \
        _Pragma("unroll")                                                     \
        for (int i = 0; i < 32; i++) a[i] = 0.f;                              \
        _Pragma("unroll 2")                                                   \
        for (int s = 0; s < 64; s++) {                                        \
            float zv = buf[s * 128 + f];                                      \
            _Pragma("unroll")                                                 \
            for (int qq = 0; qq < 8; qq++) {                                  \
                float4 a4 = *(const float4*)&At[s * 68 + n0 + qq * 4];        \
                a[qq*4+0] += a4.x * zv; a[qq*4+1] += a4.y * zv;               \
                a[qq*4+2] += a4.z * zv; a[qq*4+3] += a4.w * zv;               \
            }                                                                 \
        }                                                                     \
        _Pragma("unroll")                                                     \
        for (int i = 0; i < 32; i++)                                          \
            hreg[i] = fmaxf((a[i] + bb - mu) * sc + bt, 0.f);                 \
    }                                                                         \
    __syncthreads();                                                          \
    _Pragma("unroll")                                                         \
    for (int qq = 0; qq < 8; qq++)                                            \
        *(float4*)&buf[f * 68 + n0 + qq * 4] =                                \
            make_float4(hreg[qq*4], hreg[qq*4+1], hreg[qq*4+2], hreg[qq*4+3]);\
    __syncthreads();

#define GEMM128(WPTR)                                                         \
    {                                                                         \
        float a[32];                                                          \
        _Pragma("unroll")                                                     \
        for (int i = 0; i < 32; i++) a[i] = 0.f;                              \
        _Pragma("unroll 2")                                                   \
        for (int k = 0; k < 128; k++) {                                       \
            float wvv = WPTR[k * 128 + f];                                    \
            _Pragma("unroll")                                                 \
            for (int qq = 0; qq < 8; qq++) {                                  \
                float4 h4 = *(const float4*)&buf[k * 68 + n0 + qq * 4];       \
                a[qq*4+0] += h4.x * wvv; a[qq*4+1] += h4.y * wvv;             \
                a[qq*4+2] += h4.z * wvv; a[qq*4+3] += h4.w * wvv;             \
            }                                                                 \
        }                                                                     \
        __syncthreads();                                                      \
        _Pragma("unroll")                                                     \
        for (int i = 0; i < 32; i++) buf[(n0 + i) * 128 + f] = a[i];          \
        __syncthreads();                                                      \
    }

    LAYER128(b1, g1, be1, m1, v1)      // layer 1 -> hT in buf
    GEMM128(W2)                        // z2 -> zb in buf
    LAYER128(b2, g2, be2, m2, v2)      // layer 2 -> hT in buf

    // GEMM3: z3[n][f3] (OUT3=64)
    {
        float a[16];
        #pragma unroll
        for (int i = 0; i < 16; i++) a[i] = 0.f;
        #pragma unroll 2
        for (int k = 0; k < 128; k++) {
            float wvv = W3[k * 64 + f3];
            #pragma unroll
            for (int qq = 0; qq < 4; qq++) {
                float4 h4 = *(const float4*)&buf[k * 68 + n03 + qq * 4];
                a[qq*4+0] += h4.x * wvv; a[qq*4+1] += h4.y * wvv;
                a[qq*4+2] += h4.z * wvv; a[qq*4+3] += h4.w * wvv;
            }
        }
        __syncthreads();
        #pragma unroll
        for (int i = 0; i < 16; i++) buf[(n03 + i) * 64 + f3] = a[i];
        __syncthreads();
    }

    // layer 3 agg + BN + ReLU + pool partial
    {
        float sc = g3[f3] * rsqrtf(v3[f3] + 1e-5f);
        float mu = m3[f3], bt = be3[f3], bb = b3[f3];
        float a[16];
        #pragma unroll
        for (int i = 0; i < 16; i++) a[i] = 0.f;
        #pragma unroll 2
        for (int s = 0; s < 64; s++) {
            float zv = buf[s * 64 + f3];
            #pragma unroll
            for (int qq = 0; qq < 4; qq++) {
                float4 a4 = *(const float4*)&At[s * 68 + n03 + qq * 4];
                a[qq*4+0] += a4.x * zv; a[qq*4+1] += a4.y * zv;
                a[qq*4+2] += a4.z * zv; a[qq*4+3] += a4.w * zv;
            }
        }
        float psum = 0.f;
        #pragma unroll
        for (int i = 0; i < 16; i++)
            psum += fmaxf((a[i] + bb - mu) * sc + bt, 0.f);
        ps4[ng3 * 64 + f3] = psum;
    }
    __syncthreads();
    if (t < 64) pooled[t] = (ps4[t] + ps4[64 + t] + ps4[128 + t] + ps4[192 + t]) * (1.f / 64.f);
    __syncthreads();
    if (t == 0) {
        float l0 = fcb[0], l1 = fcb[1];
        for (int ff = 0; ff < 64; ff++) { l0 += pooled[ff] * fcw[ff * 2]; l1 += pooled[ff] * fcw[ff * 2 + 1]; }
        float mx  = fmaxf(l0, l1);
        float lse = mx + logf(expf(l0 - mx) + expf(l1 - mx));
        out[g * 2 + 0] = l0 - lse;
        out[g * 2 + 1] = l1 - lse;
    }
#undef LAYER128
#undef GEMM128
}

// ---------------------------------------------------------------- launch
extern "C" void kernel_launch(void* const* d_in, const int* in_sizes, int n_in,
                              void* d_out, int out_size, void* d_ws, size_t ws_size,
                              hipStream_t stream) {
    const float* x   = (const float*)d_in[0];
    const int*   ei  = (const int*)  d_in[1];
    const float* ew  = (const float*)d_in[2];
    const float* cw  = (const float*)d_in[4];
    const float* cb  = (const float*)d_in[5];
    const float* W1  = (const float*)d_in[6];
    const float* b1  = (const float*)d_in[7];
    const float* W2  = (const float*)d_in[8];
    const float* b2  = (const float*)d_in[9];
    const float* W3  = (const float*)d_in[10];
    const float* b3  = (const float*)d_in[11];
    const float* g1  = (const float*)d_in[12];
    const float* be1 = (const float*)d_in[13];
    const float* m1  = (const float*)d_in[14];
    const float* v1  = (const float*)d_in[15];
    const float* g2  = (const float*)d_in[16];
    const float* be2 = (const float*)d_in[17];
    const float* m2  = (const float*)d_in[18];
    const float* v2  = (const float*)d_in[19];
    const float* g3  = (const float*)d_in[20];
    const float* be3 = (const float*)d_in[21];
    const float* m3  = (const float*)d_in[22];
    const float* v3  = (const float*)d_in[23];
    const float* fcw = (const float*)d_in[24];
    const float* fcb = (const float*)d_in[25];
    float* out = (float*)d_out;

    float* z   = (float*)d_ws;                            // 16,777,216 B
    short* wPf = (short*)((char*)d_ws + 16777216);        // 8,192 B
    short* w1f = (short*)((char*)d_ws + 16785408);        // 1,228,800 B

    pack_w  <<<2,   256, 0, stream>>>(cw, wPf);
    pack_w1 <<<300, 256, 0, stream>>>(W1, w1f);
    conv_gemm1_mfma<<<NG, 256, 0, stream>>>(x, wPf, cb, w1f, z);
    graph_block<<<NG, 256, 0, stream>>>(z, ei, ew,
        b1, g1, be1, m1, v1, W2,
        b2, g2, be2, m2, v2, W3,
        b3, g3, be3, m3, v3, fcw, fcb, out);
}